// Round 1
// baseline (713.146 us; speedup 1.0000x reference)
//
#include <hip/hip_runtime.h>

// Problem constants (from reference)
constexpr int L  = 32;
constexpr int K  = 4;
constexpr int D  = 1024;
constexpr int QO = 1024;
constexpr int KV = 256;
constexpr int FF = 2816;

// Grid layout: 5 matrix-groups per layer (q,k,v,o,mlp-fused), 64 blocks per
// (layer, group) covering D=1024 rows at 16 rows/block (4 waves x 4 rows).
constexpr int PROJ_BLOCKS = L * 5 * 64;          // 10240
constexpr int RES_F4      = L * 7 * K * D / 4;   // 229376 float4s of residual
constexpr int RES_BLOCKS  = RES_F4 / 256;        // 896 (exact)
constexpr int TOTAL_BLOCKS = PROJ_BLOCKS + RES_BLOCKS;

// One wave computes 4 output rows d0..d0+3 of out[l, m(s), 1, k, :] for all
// NK activation vectors, streaming the weight rows once (coalesced float4).
// Activations are tiny (4-44 KB per layer/group) -> read from global, L1/L2 hot.
template<int NK, int NCH>
__device__ __forceinline__ void proj_rows(
    const float* __restrict__ W,    // layer's weight, [D, I] row-major
    const float* __restrict__ act,  // layer's activations, [NK, I] row-major
    float* __restrict__ out, int l, int g, int d0, int lane)
{
    constexpr int I = NCH * 256;

    float acc[NK][4];
    #pragma unroll
    for (int kk = 0; kk < NK; ++kk)
        #pragma unroll
        for (int r = 0; r < 4; ++r) acc[kk][r] = 0.f;

    const float* wp = W + d0 * I + lane * 4;
    const float* ap = act + lane * 4;

    // Chunk loop: each iter the wave covers 256 columns (lane*4 .. +3).
    // unroll 1: keep VGPR pressure bounded on the NK=12 path; the 16
    // independent loads inside one iter already give MLP for latency hiding.
    #pragma unroll 1
    for (int c = 0; c < NCH; ++c) {
        float4 a[NK];
        #pragma unroll
        for (int kk = 0; kk < NK; ++kk)
            a[kk] = *(const float4*)(ap + kk * I + c * 256);
        #pragma unroll
        for (int r = 0; r < 4; ++r) {
            float4 w = *(const float4*)(wp + r * I + c * 256);
            #pragma unroll
            for (int kk = 0; kk < NK; ++kk) {
                acc[kk][r] = fmaf(w.x, a[kk].x, acc[kk][r]);
                acc[kk][r] = fmaf(w.y, a[kk].y, acc[kk][r]);
                acc[kk][r] = fmaf(w.z, a[kk].z, acc[kk][r]);
                acc[kk][r] = fmaf(w.w, a[kk].w, acc[kk][r]);
            }
        }
    }

    // Full-wave butterfly reduce each accumulator (every lane ends with the sum).
    #pragma unroll
    for (int kk = 0; kk < NK; ++kk)
        #pragma unroll
        for (int r = 0; r < 4; ++r) {
            float v = acc[kk][r];
            #pragma unroll
            for (int mask = 32; mask >= 1; mask >>= 1)
                v += __shfl_xor(v, mask, 64);
            acc[kk][r] = v;
        }

    if (lane == 0) {
        #pragma unroll
        for (int kk = 0; kk < NK; ++kk) {
            // MODULE_ORDER = [q,k,v,gate,up,o,down] -> m index
            int m, k;
            if      (g == 0) { m = 0; k = kk; }
            else if (g == 1) { m = 1; k = kk; }
            else if (g == 2) { m = 2; k = kk; }
            else if (g == 3) { m = 5; k = kk; }
            else { int mp = kk >> 2; m = (mp == 0) ? 3 : (mp == 1) ? 4 : 6; k = kk & 3; }
            int base = (((l * 7 + m) * 2 + 1) * K + k) * D + d0;  // s=1 (proj) half
            #pragma unroll
            for (int r = 0; r < 4; ++r)
                out[base + r] = acc[kk][r];
        }
    }
}

__global__ __launch_bounds__(256) void bse_kernel(
    const float* __restrict__ residual, const float* __restrict__ cq,
    const float* __restrict__ ck,       const float* __restrict__ cv,
    const float* __restrict__ co,       const float* __restrict__ cmlp,
    const float* __restrict__ Wq,       const float* __restrict__ Wk,
    const float* __restrict__ Wv,       const float* __restrict__ Wo,
    const float* __restrict__ Wd,       float* __restrict__ out)
{
    int bid = blockIdx.x;
    int tid = threadIdx.x;

    if (bid < PROJ_BLOCKS) {
        int grp  = bid >> 6;             // (layer, group)
        int g    = grp % 5;
        int l    = grp / 5;
        int d0   = ((bid & 63) << 4) + ((tid >> 6) << 2);  // 16 rows/block, 4/wave
        int lane = tid & 63;

        if (g == 0)
            proj_rows<4, 4>(Wq + (size_t)l * D * QO, cq + l * K * QO, out, l, 0, d0, lane);
        else if (g == 1)
            proj_rows<4, 1>(Wk + (size_t)l * D * KV, ck + l * K * KV, out, l, 1, d0, lane);
        else if (g == 2)
            proj_rows<4, 1>(Wv + (size_t)l * D * KV, cv + l * K * KV, out, l, 2, d0, lane);
        else if (g == 3)
            proj_rows<4, 4>(Wo + (size_t)l * D * QO, co + l * K * QO, out, l, 3, d0, lane);
        else
            // W_down read ONCE, all 12 outputs (gate/up/down x K) computed together.
            proj_rows<12, 11>(Wd + (size_t)l * D * FF, cmlp + (size_t)l * 12 * FF, out, l, 4, d0, lane);
    } else {
        // Residual copy into the s=0 slots, float4-vectorized, fully coalesced.
        int f = (bid - PROJ_BLOCKS) * 256 + tid;    // float4 index < RES_F4
        float4 v = ((const float4*)residual)[f];
        int d4   = f & 255;                          // d/4 within D
        int rest = f >> 8;                           // (l*7+m)*K + k
        int k    = rest & 3;
        int lm   = rest >> 2;                        // l*7+m
        ((float4*)out)[(lm * 2 * K + k) * 256 + d4] = v;
    }
}

extern "C" void kernel_launch(void* const* d_in, const int* in_sizes, int n_in,
                              void* d_out, int out_size, void* d_ws, size_t ws_size,
                              hipStream_t stream) {
    const float* residual = (const float*)d_in[0];
    const float* cq   = (const float*)d_in[1];
    const float* ck   = (const float*)d_in[2];
    const float* cv   = (const float*)d_in[3];
    const float* co   = (const float*)d_in[4];
    const float* cmlp = (const float*)d_in[5];
    const float* Wq   = (const float*)d_in[6];
    const float* Wk   = (const float*)d_in[7];
    const float* Wv   = (const float*)d_in[8];
    const float* Wo   = (const float*)d_in[9];
    const float* Wd   = (const float*)d_in[10];
    float* out = (float*)d_out;

    bse_kernel<<<TOTAL_BLOCKS, 256, 0, stream>>>(
        residual, cq, ck, cv, co, cmlp, Wq, Wk, Wv, Wo, Wd, out);
}

// Round 2
// 710.108 us; speedup vs baseline: 1.0043x; 1.0043x over previous
//
#include <hip/hip_runtime.h>

// Problem constants
constexpr int L  = 32;
constexpr int K  = 4;
constexpr int D  = 1024;
constexpr int QO = 1024;
constexpr int KV = 256;
constexpr int FF = 2816;

// Per-layer block layout:
//   r in [0,32)    : Wq, 32 rows/block (8 rows/wave), I=1024
//   r in [32,64)   : Wo, same shape
//   r in [64,96)   : Wk, 32 rows/block, I=256
//   r in [96,128)  : Wv
//   r in [128,192) : Wd, 16 rows/block (4 rows/wave), I=2816, all 12 acts fused
constexpr int PER_LAYER   = 192;
constexpr int PROJ_BLOCKS = L * PER_LAYER;      // 6144
constexpr int RES_F4      = L * 7 * K * D / 4;  // 229376
constexpr int RES_BLOCKS  = RES_F4 / 256;       // 896
constexpr int TOTAL_BLOCKS = PROJ_BLOCKS + RES_BLOCKS;

// Inner streaming loop: NCH chunks of 256 columns. Acts come from LDS
// (lgkmcnt path, short latency), weights stream from global (the ONLY thing
// in the vmcnt queue). Full unroll -> up to NCH*NR weight loads in flight.
template<int NCH, int NR, int NK, int LDST>
__device__ __forceinline__ void dot_chunks(const float* __restrict__ w0,
                                           size_t rstride,
                                           const float* __restrict__ lds,
                                           int lane, float (&acc)[NK][NR])
{
    #pragma unroll
    for (int c = 0; c < NCH; ++c) {
        float4 a[NK];
        #pragma unroll
        for (int kk = 0; kk < NK; ++kk)
            a[kk] = *(const float4*)(lds + kk * LDST + c * 256 + lane * 4);
        #pragma unroll
        for (int rr = 0; rr < NR; ++rr) {
            float4 w = *(const float4*)(w0 + (size_t)rr * rstride + c * 256 + lane * 4);
            #pragma unroll
            for (int kk = 0; kk < NK; ++kk) {
                acc[kk][rr] = fmaf(w.x, a[kk].x, acc[kk][rr]);
                acc[kk][rr] = fmaf(w.y, a[kk].y, acc[kk][rr]);
                acc[kk][rr] = fmaf(w.z, a[kk].z, acc[kk][rr]);
                acc[kk][rr] = fmaf(w.w, a[kk].w, acc[kk][rr]);
            }
        }
    }
}

template<int NK, int NR>
__device__ __forceinline__ void butterfly(float (&acc)[NK][NR])
{
    #pragma unroll
    for (int kk = 0; kk < NK; ++kk)
        #pragma unroll
        for (int rr = 0; rr < NR; ++rr) {
            float v = acc[kk][rr];
            #pragma unroll
            for (int mask = 32; mask >= 1; mask >>= 1)
                v += __shfl_xor(v, mask, 64);
            acc[kk][rr] = v;
        }
}

__global__ __launch_bounds__(256) void bse_kernel(
    const float* __restrict__ residual, const float* __restrict__ cq,
    const float* __restrict__ ck,       const float* __restrict__ cv,
    const float* __restrict__ co,       const float* __restrict__ cmlp,
    const float* __restrict__ Wq,       const float* __restrict__ Wk,
    const float* __restrict__ Wv,       const float* __restrict__ Wo,
    const float* __restrict__ Wd,       float* __restrict__ out)
{
    __shared__ float lds[12 * 512];          // 24 KB: g=4 section buffer; others use prefix
    int bid = blockIdx.x;
    int tid = threadIdx.x;

    if (bid >= PROJ_BLOCKS) {
        // Residual copy into s=0 slots, float4 coalesced.
        int f = (bid - PROJ_BLOCKS) * 256 + tid;
        float4 v = ((const float4*)residual)[f];
        int d4   = f & 255;
        int rest = f >> 8;
        int k    = rest & 3;
        int lm   = rest >> 2;
        ((float4*)out)[(lm * 2 * K + k) * 256 + d4] = v;
        return;
    }

    int l    = bid / PER_LAYER;
    int r    = bid % PER_LAYER;
    int lane = tid & 63;
    int wave = tid >> 6;
    float4* l4 = (float4*)lds;

    if (r < 64) {
        // ---- Wq / Wo: I=1024, 32 rows/block, 8 rows/wave ----
        bool isQ = r < 32;
        int  sub = r & 31;
        int  m   = isQ ? 0 : 5;
        const float* Wp = (isQ ? Wq : Wo) + (size_t)l * D * QO;
        const float* ap = (isQ ? cq : co) + (size_t)l * K * QO;

        const float4* a4 = (const float4*)ap;           // 1024 float4 = 16 KB
        #pragma unroll
        for (int i = 0; i < 4; ++i) l4[tid + i * 256] = a4[tid + i * 256];
        __syncthreads();

        int d0 = sub * 32 + wave * 8;
        float acc[4][8] = {};
        const float* wbase = Wp + (size_t)d0 * QO;
        dot_chunks<2, 8, 4, 1024>(wbase,       QO, lds,       lane, acc);
        dot_chunks<2, 8, 4, 1024>(wbase + 512, QO, lds + 512, lane, acc);
        butterfly<4, 8>(acc);
        if (lane == 0) {
            #pragma unroll
            for (int k = 0; k < 4; ++k) {
                int base = (((l * 7 + m) * 2 + 1) * K + k) * D + d0;
                *(float4*)&out[base]     = make_float4(acc[k][0], acc[k][1], acc[k][2], acc[k][3]);
                *(float4*)&out[base + 4] = make_float4(acc[k][4], acc[k][5], acc[k][6], acc[k][7]);
            }
        }
    } else if (r < 128) {
        // ---- Wk / Wv: I=256, 32 rows/block, 8 rows/wave, single chunk ----
        bool isK = r < 96;
        int  sub = (r - 64) & 31;
        int  m   = isK ? 1 : 2;
        const float* Wp = (isK ? Wk : Wv) + (size_t)l * D * KV;
        const float* ap = (isK ? ck : cv) + (size_t)l * K * KV;

        l4[tid] = ((const float4*)ap)[tid];             // 256 float4 = 4 KB
        __syncthreads();

        int d0 = sub * 32 + wave * 8;
        float acc[4][8] = {};
        const float* wbase = Wp + (size_t)d0 * KV;
        dot_chunks<1, 8, 4, 256>(wbase, KV, lds, lane, acc);
        butterfly<4, 8>(acc);
        if (lane == 0) {
            #pragma unroll
            for (int k = 0; k < 4; ++k) {
                int base = (((l * 7 + m) * 2 + 1) * K + k) * D + d0;
                *(float4*)&out[base]     = make_float4(acc[k][0], acc[k][1], acc[k][2], acc[k][3]);
                *(float4*)&out[base + 4] = make_float4(acc[k][4], acc[k][5], acc[k][6], acc[k][7]);
            }
        }
    } else {
        // ---- Wd: I=2816, 16 rows/block, 4 rows/wave, all 12 act vectors.
        // Acts streamed through LDS in 512-column sections (5x512 + 256).
        int sub = r - 128;
        int d0  = sub * 16 + wave * 4;
        float acc[12][4] = {};
        const float*  wbase = Wd + ((size_t)l * D + d0) * FF;
        const float4* a4    = (const float4*)(cmlp + (size_t)l * 12 * FF);  // rows of 704 f4

        #pragma unroll 1
        for (int sec = 0; sec < 5; ++sec) {
            __syncthreads();
            int c0_4 = sec * 128;
            #pragma unroll
            for (int i = tid; i < 12 * 128; i += 256) {
                int kk = i >> 7, c4 = i & 127;
                l4[kk * 128 + c4] = a4[kk * 704 + c0_4 + c4];
            }
            __syncthreads();
            dot_chunks<2, 4, 12, 512>(wbase + sec * 512, FF, lds, lane, acc);
        }
        // tail section: 256 columns
        __syncthreads();
        #pragma unroll
        for (int i = tid; i < 12 * 64; i += 256) {
            int kk = i >> 6, c4 = i & 63;
            l4[kk * 128 + c4] = a4[kk * 704 + 640 + c4];
        }
        __syncthreads();
        dot_chunks<1, 4, 12, 512>(wbase + 2560, FF, lds, lane, acc);

        butterfly<12, 4>(acc);
        if (lane == 0) {
            #pragma unroll
            for (int kk = 0; kk < 12; ++kk) {
                int mp = kk >> 2, k = kk & 3;
                int m  = (mp == 0) ? 3 : (mp == 1) ? 4 : 6;
                int base = (((l * 7 + m) * 2 + 1) * K + k) * D + d0;
                *(float4*)&out[base] = make_float4(acc[kk][0], acc[kk][1], acc[kk][2], acc[kk][3]);
            }
        }
    }
}

extern "C" void kernel_launch(void* const* d_in, const int* in_sizes, int n_in,
                              void* d_out, int out_size, void* d_ws, size_t ws_size,
                              hipStream_t stream) {
    const float* residual = (const float*)d_in[0];
    const float* cq   = (const float*)d_in[1];
    const float* ck   = (const float*)d_in[2];
    const float* cv   = (const float*)d_in[3];
    const float* co   = (const float*)d_in[4];
    const float* cmlp = (const float*)d_in[5];
    const float* Wq   = (const float*)d_in[6];
    const float* Wk   = (const float*)d_in[7];
    const float* Wv   = (const float*)d_in[8];
    const float* Wo   = (const float*)d_in[9];
    const float* Wd   = (const float*)d_in[10];
    float* out = (float*)d_out;

    bse_kernel<<<TOTAL_BLOCKS, 256, 0, stream>>>(
        residual, cq, ck, cv, co, cmlp, Wq, Wk, Wv, Wo, Wd, out);
}